// Round 13
// baseline (239.956 us; speedup 1.0000x reference)
//
#include <hip/hip_runtime.h>
#include <cfloat>
#include <cmath>

// ---------------------------------------------------------------------------
// UncertaintyGAT. Round-13: half-wave-per-node agg12.
//  Each 32-lane half-wave owns one dst node; a lane gathers uint2 (8B) so 32
//  lanes cover the 256B z-row -> per wave-instruction TWO edges are processed
//  (global-load instrs/edge halved, LDS instrs/edge halved, VALU/edge ~2/3).
//  Bytes unchanged (irreducible: every fetched byte consumed); r10 proved
//  ordering can't raise L2 hits; r12 proved VALU alone wasn't binding --
//  this cuts ALL per-edge issue streams together. Unroll 4 keeps VGPR<=36
//  (r7 lesson). Launch structure = r12 (safe w.r.t. zp<->tmp alias).
// ---------------------------------------------------------------------------

#define CBG 256
#define CAPC 12288
#define TILE 4096
#define BIMG 10240

typedef __attribute__((ext_vector_type(8))) short short8v;
typedef __attribute__((ext_vector_type(4))) float f32x4;

__device__ __forceinline__ float lrelu(float x) { return x > 0.f ? x : 0.2f * x; }

__device__ __forceinline__ uint32_t bf16_rne(float f) {
  uint32_t u = __float_as_uint(f);
  return (u + 0x7fffu + ((u >> 16) & 1u)) >> 16;
}
__device__ __forceinline__ uint32_t pack_hilo(float v) {
  uint32_t h = bf16_rne(v);
  float r = v - __uint_as_float(h << 16);
  return (h << 16) | bf16_rne(r);
}

// ---------------- prep: W split+swizzle (blocks 0..23) + scount zero -------
__global__ __launch_bounds__(256) void prep_kernel(
    const float* __restrict__ W0, const float* __restrict__ W1,
    const float* __restrict__ W2, short* __restrict__ Whi0,
    short* __restrict__ Wlo0, short* __restrict__ Whi1, short* __restrict__ Wlo1,
    short* __restrict__ Whi2, short* __restrict__ Wlo2,
    int* __restrict__ scount, int ncb) {
  if (blockIdx.x >= 24) {
    for (int i = threadIdx.x; i < ncb; i += 256) scount[i] = 0;
    return;
  }
  int which = blockIdx.x >> 3;
  const float* W = which == 0 ? W0 : (which == 1 ? W1 : W2);
  short* Whi = which == 0 ? Whi0 : (which == 1 ? Whi1 : Whi2);
  short* Wlo = which == 0 ? Wlo0 : (which == 1 ? Wlo1 : Wlo2);
  int fid = (blockIdx.x & 7) * 256 + threadIdx.x;  // 0..2047
  int lane = fid & 63;
  int cq = fid >> 6;
  int q = cq >> 3, c = cq & 7;
  int col = c * 16 + (lane & 15);
  int k0 = q * 32 + (lane >> 4) * 8;
#pragma unroll
  for (int j = 0; j < 8; j++) {
    float v = W[(k0 + j) * 128 + col];
    uint32_t h = bf16_rne(v);
    float r = v - __uint_as_float(h << 16);
    Whi[fid * 8 + j] = (short)h;
    Wlo[fid * 8 + j] = (short)bf16_rne(r);
  }
}

// ---------------- CSR build (n < 65536 path) ----------------
__global__ __launch_bounds__(256) void bucketA_kernel(
    const int* __restrict__ src, const int* __restrict__ dst,
    int* __restrict__ scount, uint32_t* __restrict__ tmp, int e, int ncb) {
  __shared__ int cnt[256];
  __shared__ int lscan[256];
  __shared__ int gbase[256];
  __shared__ uint32_t image[TILE];
  const int t = threadIdx.x;
  const int e0 = blockIdx.x * TILE;
  const int ne = min(TILE, e - e0);

  for (int i = t; i < 256; i += 256) cnt[i] = 0;
  __syncthreads();
  for (int i = t; i < ne; i += 256) atomicAdd(&cnt[dst[e0 + i] >> 8], 1);
  __syncthreads();
  if (t < 64) {
    int carry = 0;
    for (int base = 0; base < ncb; base += 64) {
      int idx = base + t;
      int c = (idx < ncb) ? cnt[idx] : 0;
      int v = c;
#pragma unroll
      for (int off = 1; off < 64; off <<= 1) {
        int u = __shfl_up(v, off, 64);
        if (t >= off) v += u;
      }
      if (idx < ncb) lscan[idx] = carry + v - c;
      carry += __shfl(v, 63, 64);
    }
  }
  __syncthreads();
  for (int b = t; b < ncb; b += 256)
    gbase[b] = (cnt[b] > 0) ? atomicAdd(&scount[b], cnt[b]) : 0;
  __syncthreads();
  for (int b = t; b < ncb; b += 256) cnt[b] = 0;
  __syncthreads();
  for (int i = t; i < ne; i += 256) {
    int d = dst[e0 + i], s = src[e0 + i];
    int b = d >> 8;
    int r = atomicAdd(&cnt[b], 1);
    image[lscan[b] + r] =
        (uint32_t)s | ((uint32_t)(d & 255) << 16) | ((uint32_t)b << 24);
  }
  __syncthreads();
  for (int j = t; j < ne; j += 256) {
    uint32_t w = image[j];
    int b = w >> 24;
    int pos = gbase[b] + (j - lscan[b]);
    if (pos < CAPC) tmp[(size_t)b * CAPC + pos] = w & 0xFFFFFFu;
  }
}

// ---------------- bucketB body: key = dst_local*8 + src_block --------------
__device__ __forceinline__ void bucketB_body(
    int b, char* smem, const uint32_t* __restrict__ tmp,
    const int* __restrict__ scount, int* __restrict__ row_start,
    int* __restrict__ csr_src, int n, int ncb, int e, int sshift) {
  int* cnt2 = (int*)smem;                      // 2048 (hist -> cursor)
  int* wsum = cnt2 + 2048;                     // 4
  int* s_base = wsum + 4;                      // 1
  uint32_t* image = (uint32_t*)(smem + 8224);  // BIMG
  const int t = threadIdx.x, lane = t & 63, wid = t >> 6;

  if (t < 64) {
    int part = 0;
    for (int idx = lane; idx < b; idx += 64) part += scount[idx];
#pragma unroll
    for (int off = 32; off; off >>= 1) part += __shfl_xor(part, off, 64);
    if (lane == 0) *s_base = part;
  }
#pragma unroll
  for (int j = 0; j < 8; j++) cnt2[t * 8 + j] = 0;
  __syncthreads();
  const int total = min(scount[b], CAPC);
  const int base = *s_base;
  const uint32_t* strm = tmp + (size_t)b * CAPC;

  for (int i = t; i < total; i += 256) {
    uint32_t w = strm[i];
    int key = (((w >> 16) & 255) << 3) + ((w & 0xFFFFu) >> sshift);
    atomicAdd(&cnt2[key], 1);
  }
  __syncthreads();
  int c8[8];
  int run = 0;
#pragma unroll
  for (int j = 0; j < 8; j++) { int x = cnt2[t * 8 + j]; c8[j] = run; run += x; }
  int c = run, v = c;
#pragma unroll
  for (int off = 1; off < 64; off <<= 1) {
    int u = __shfl_up(v, off, 64);
    if (lane >= off) v += u;
  }
  if (lane == 63) wsum[wid] = v;
  __syncthreads();
  if (t == 0) {
    int acc = 0;
#pragma unroll
    for (int w = 0; w < 4; w++) { int x = wsum[w]; wsum[w] = acc; acc += x; }
  }
  __syncthreads();
  int ex = wsum[wid] + v - c;
#pragma unroll
  for (int j = 0; j < 8; j++) cnt2[t * 8 + j] = ex + c8[j];
  int d = b * CBG + t;
  if (d < n) row_start[d] = base + ex;
  if (b == 0 && t == 0) row_start[n] = e;
  __syncthreads();
  for (int i = t; i < total; i += 256) {
    uint32_t w = strm[i];
    uint32_t s = w & 0xFFFFu;
    int key = (((w >> 16) & 255) << 3) + (s >> sshift);
    int pos = atomicAdd(&cnt2[key], 1);
    if (pos < BIMG) image[pos] = s;
    else csr_src[base + pos] = (int)s;
  }
  __syncthreads();
  const int lim = total < BIMG ? total : BIMG;
  for (int j = t; j < lim; j += 256) csr_src[base + j] = (int)image[j];
}

// ---------------- MFMA GEMM body (uses caller LDS; 34.8KB) ----------------
template <int MODE>
__device__ __forceinline__ void mfmm_body(
    int bid, char* smem,
    const uint32_t* __restrict__ Xp, const short* __restrict__ Whi,
    const short* __restrict__ Wlo, const float* __restrict__ bias,
    uint32_t* __restrict__ Hp, uint32_t* __restrict__ zp,
    float2* __restrict__ el2, float2* __restrict__ er2,
    const float* __restrict__ al, const float* __restrict__ ar, int n,
    const float* __restrict__ emb, const int* __restrict__ ids,
    const float* __restrict__ feat) {
  short* Ahi = (short*)smem;
  short* Alo = Ahi + 64 * 136;
  const int t = threadIdx.x;
  const int nb = bid * 64;

  for (int idx = t; idx < 64 * 32; idx += 256) {
    int nl = idx >> 5, k4 = (idx & 31) << 2;
    int node = nb + nl;
    uint32_t h01 = 0, h23 = 0, l01 = 0, l23 = 0;
    if (node < n) {
      if (MODE == 1) {
        uint4 w = *(const uint4*)&Xp[(size_t)node * 128 + k4];
        h01 = (w.x >> 16) | (w.y & 0xffff0000u);
        l01 = (w.x & 0xffffu) | (w.y << 16);
        h23 = (w.z >> 16) | (w.w & 0xffff0000u);
        l23 = (w.z & 0xffffu) | (w.w << 16);
      } else {
        float4 v;
        if (k4 < 64) v = *(const float4*)&emb[(size_t)ids[node] * 64 + k4];
        else         v = *(const float4*)&feat[(size_t)node * 64 + (k4 - 64)];
        uint32_t a0 = bf16_rne(v.x), a1 = bf16_rne(v.y);
        uint32_t a2 = bf16_rne(v.z), a3 = bf16_rne(v.w);
        h01 = a0 | (a1 << 16);
        h23 = a2 | (a3 << 16);
        l01 = bf16_rne(v.x - __uint_as_float(a0 << 16)) |
              (bf16_rne(v.y - __uint_as_float(a1 << 16)) << 16);
        l23 = bf16_rne(v.z - __uint_as_float(a2 << 16)) |
              (bf16_rne(v.w - __uint_as_float(a3 << 16)) << 16);
      }
    }
    *(uint2*)&Ahi[nl * 136 + k4] = make_uint2(h01, h23);
    *(uint2*)&Alo[nl * 136 + k4] = make_uint2(l01, l23);
  }
  __syncthreads();

  const int lane = t & 63, wv = t >> 6;
  const int r16 = lane & 15, g = lane >> 4;
  const int arow = (wv * 16 + r16) * 136;

  f32x4 acc[8];
#pragma unroll
  for (int c = 0; c < 8; c++) acc[c] = (f32x4){0.f, 0.f, 0.f, 0.f};

#pragma unroll
  for (int q = 0; q < 4; q++) {
    int ka = q * 32 + g * 8;
    short8v ahi = *(const short8v*)&Ahi[arow + ka];
    short8v alo = *(const short8v*)&Alo[arow + ka];
#pragma unroll
    for (int c = 0; c < 8; c++) {
      short8v bhi = *(const short8v*)&Whi[(((q * 8 + c) * 64) + lane) * 8];
      short8v blo = *(const short8v*)&Wlo[(((q * 8 + c) * 64) + lane) * 8];
      acc[c] = __builtin_amdgcn_mfma_f32_16x16x32_bf16(ahi, bhi, acc[c], 0, 0, 0);
      acc[c] = __builtin_amdgcn_mfma_f32_16x16x32_bf16(ahi, blo, acc[c], 0, 0, 0);
      acc[c] = __builtin_amdgcn_mfma_f32_16x16x32_bf16(alo, bhi, acc[c], 0, 0, 0);
    }
  }

  const int node_base = nb + wv * 16;
  if (MODE == 0) {
#pragma unroll
    for (int c = 0; c < 8; c++) {
      int col = c * 16 + r16;
      float bv = bias[col];
#pragma unroll
      for (int r = 0; r < 4; r++) {
        int node = node_base + g * 4 + r;
        if (node < n) {
          float v = fmaxf(acc[c][r] + bv, 0.f);
          Hp[(size_t)node * 128 + col] = pack_hilo(v);
        }
      }
    }
  } else {
    float p0l[4] = {0, 0, 0, 0}, p1l[4] = {0, 0, 0, 0};
    float p0r[4] = {0, 0, 0, 0}, p1r[4] = {0, 0, 0, 0};
#pragma unroll
    for (int c = 0; c < 8; c++) {
      int col = c * 16 + r16;
      float av = al[col], rv = ar[col];
#pragma unroll
      for (int r = 0; r < 4; r++) {
        if (c < 4) { p0l[r] = fmaf(acc[c][r], av, p0l[r]); p0r[r] = fmaf(acc[c][r], rv, p0r[r]); }
        else       { p1l[r] = fmaf(acc[c][r], av, p1l[r]); p1r[r] = fmaf(acc[c][r], rv, p1r[r]); }
      }
    }
#pragma unroll
    for (int c = 0; c < 8; c++) {
#pragma unroll
      for (int r = 0; r < 4; r++) {
        float other = __shfl_xor(acc[c][r], 1, 64);
        int node = node_base + g * 4 + r;
        if (!(lane & 1) && node < n) {
          uint32_t w = bf16_rne(acc[c][r]) | (bf16_rne(other) << 16);
          zp[(size_t)node * 64 + c * 8 + (r16 >> 1)] = w;
        }
      }
    }
#pragma unroll
    for (int off = 1; off < 16; off <<= 1) {
#pragma unroll
      for (int r = 0; r < 4; r++) {
        p0l[r] += __shfl_xor(p0l[r], off, 64);
        p1l[r] += __shfl_xor(p1l[r], off, 64);
        p0r[r] += __shfl_xor(p0r[r], off, 64);
        p1r[r] += __shfl_xor(p1r[r], off, 64);
      }
    }
    if (r16 == 0) {
#pragma unroll
      for (int r = 0; r < 4; r++) {
        int node = node_base + g * 4 + r;
        if (node < n) {
          el2[node] = make_float2(p0l[r], p1l[r]);
          er2[node] = make_float2(p0r[r], p1r[r]);
        }
      }
    }
  }
}

// ---- fused: bucketB (blocks [0,ncbB)) + dense GEMM (writes Hp only; safe
// w.r.t. the zp<->tmp alias since zp is first written by the LATER mfmm1) ----
__global__ __launch_bounds__(256) void mfmm0_bktB_kernel(
    const uint32_t* __restrict__ tmp, const int* __restrict__ scount,
    int* __restrict__ row_start, int* __restrict__ csr_src, int ncbB,
    const short* __restrict__ Whi, const short* __restrict__ Wlo,
    const float* __restrict__ bias, uint32_t* __restrict__ Hp, int n, int ncb,
    int e, int sshift, const float* __restrict__ emb, const int* __restrict__ ids,
    const float* __restrict__ feat) {
  __shared__ __align__(16) char smem[49200];
  if ((int)blockIdx.x < ncbB) {
    bucketB_body(blockIdx.x, smem, tmp, scount, row_start, csr_src, n, ncb, e,
                 sshift);
  } else {
    mfmm_body<0>(blockIdx.x - ncbB, smem, nullptr, Whi, Wlo, bias, Hp,
                 nullptr, nullptr, nullptr, nullptr, nullptr, n, emb, ids, feat);
  }
}

__global__ __launch_bounds__(256) void mfmm1_kernel(
    const uint32_t* __restrict__ Xp, const short* __restrict__ Whi,
    const short* __restrict__ Wlo, uint32_t* __restrict__ zp,
    float2* __restrict__ el2, float2* __restrict__ er2,
    const float* __restrict__ al, const float* __restrict__ ar, int n) {
  __shared__ __align__(16) char smem[34816];
  mfmm_body<1>(blockIdx.x, smem, Xp, Whi, Wlo, nullptr, nullptr, zp, el2, er2,
               al, ar, n, nullptr, nullptr, nullptr);
}

// ---------------- fallback path (n >= 65536) ----------------
__global__ void hist_kernel(const int* __restrict__ dst, int* __restrict__ cnt, int e) {
  for (int i = blockIdx.x * blockDim.x + threadIdx.x; i < e; i += gridDim.x * blockDim.x)
    atomicAdd(&cnt[dst[i]], 1);
}
__global__ void scatter_kernel(const int* __restrict__ src, const int* __restrict__ dst,
                               const int* __restrict__ row_start, int* __restrict__ cursor,
                               int* __restrict__ csr_src, int e) {
  for (int i = blockIdx.x * blockDim.x + threadIdx.x; i < e; i += gridDim.x * blockDim.x) {
    int d = dst[i];
    int pos = atomicAdd(&cursor[d], 1);
    csr_src[row_start[d] + pos] = src[i];
  }
}
__global__ __launch_bounds__(1024) void scan1_kernel(const int* __restrict__ cnt,
                                                     int* __restrict__ row_start,
                                                     int* __restrict__ bsum, int n) {
  __shared__ int wsum[16];
  const int t = threadIdx.x, lane = t & 63, wid = t >> 6;
  int i = blockIdx.x * 1024 + t;
  int c = (i < n) ? cnt[i] : 0;
  int v = c;
#pragma unroll
  for (int off = 1; off < 64; off <<= 1) {
    int u = __shfl_up(v, off, 64);
    if (lane >= off) v += u;
  }
  if (lane == 63) wsum[wid] = v;
  __syncthreads();
  if (t == 0) {
    int acc = 0;
#pragma unroll
    for (int w = 0; w < 16; w++) { int x = wsum[w]; wsum[w] = acc; acc += x; }
    bsum[blockIdx.x] = acc;
  }
  __syncthreads();
  if (i < n) row_start[i] = wsum[wid] + v - c;
}
__global__ __launch_bounds__(64) void scan2_kernel(int* __restrict__ bsum, int nb) {
  const int lane = threadIdx.x;
  int carry = 0;
  for (int base = 0; base < nb; base += 64) {
    int idx = base + lane;
    int c = (idx < nb) ? bsum[idx] : 0;
    int v = c;
#pragma unroll
    for (int off = 1; off < 64; off <<= 1) {
      int u = __shfl_up(v, off, 64);
      if (lane >= off) v += u;
    }
    if (idx < nb) bsum[idx] = carry + v - c;
    carry += __shfl(v, 63, 64);
  }
}
__global__ void scan3_kernel(int* __restrict__ row_start, const int* __restrict__ bsum,
                             int n, int e) {
  int i = blockIdx.x * blockDim.x + threadIdx.x;
  if (i < n) row_start[i] += bsum[i >> 10];
  if (i == 0) row_start[n] = e;
}

// ---------------- GAT aggregation: half-wave (32 lanes) per dst node -------
// Lane l32 gathers uint2 (8B) -> 32 lanes cover the 256B z-row; two edges
// (one per half-wave) per wave instruction. Lane owns dims 4*l32..4*l32+3;
// head = l32>>4. Unroll 4 (VGPR budget, r7 lesson).
#define CAP 256
__global__ __launch_bounds__(256) void agg12_kernel(
    const uint32_t* __restrict__ zp, const float2* __restrict__ el2,
    const float2* __restrict__ er2, const int* __restrict__ row_start,
    const int* __restrict__ csr_src, const float* __restrict__ bias,
    uint32_t* __restrict__ Hp,
    const float* __restrict__ ow, const float* __restrict__ oal,
    const float* __restrict__ oar, float* __restrict__ z3,
    float* __restrict__ el3, float* __restrict__ er3, int n, int fuse_out) {
  __shared__ float ex2[8][2][CAP];
  __shared__ int sc[8][CAP];
  const int hw = threadIdx.x >> 5, l32 = threadIdx.x & 31;
  const int node = blockIdx.x * 8 + hw;
  const bool valid = node < n;
  int rs = 0, deg = 0;
  float er0 = 0.f, er1 = 0.f;
  if (valid) {
    rs = row_start[node];
    deg = row_start[node + 1] - rs;
    float2 e2 = er2[node];
    er0 = e2.x; er1 = e2.y;
  }
  const int cdeg = deg < CAP ? deg : CAP;

  // phase 1: per half-wave, gather el, exp, cache (s<<8, x0, x1), sum
  float sp0 = 0.f, sp1 = 0.f;
  for (int i = l32; i < deg; i += 32) {
    int s = csr_src[rs + i];
    float2 l = el2[s];
    float x0 = __expf(lrelu(l.x + er0));
    float x1 = __expf(lrelu(l.y + er1));
    if (i < CAP) { sc[hw][i] = s << 8; ex2[hw][0][i] = x0; ex2[hw][1][i] = x1; }
    sp0 += x0; sp1 += x1;
  }
#pragma unroll
  for (int off = 16; off; off >>= 1) {
    sp0 += __shfl_xor(sp0, off, 64);
    sp1 += __shfl_xor(sp1, off, 64);
  }
  __syncthreads();

  // phase 2: uint2 gather (8B/lane), unroll 4
  const int head = l32 >> 4;
  const float* exh = ex2[hw][head];
  const char* zpB = (const char*)zp + (size_t)l32 * 8;
  float a0 = 0.f, a1 = 0.f, a2 = 0.f, a3 = 0.f;
  int i = 0;
  for (; i + 4 <= cdeg; i += 4) {
    uint2 zw[4];
    float xh[4];
#pragma unroll
    for (int u = 0; u < 4; u++) {
      int off = sc[hw][i + u];
      xh[u] = exh[i + u];
      zw[u] = *(const uint2*)(zpB + off);
    }
#pragma unroll
    for (int u = 0; u < 4; u++) {
      a0 = fmaf(xh[u], __uint_as_float(zw[u].x << 16), a0);
      a1 = fmaf(xh[u], __uint_as_float(zw[u].x & 0xffff0000u), a1);
      a2 = fmaf(xh[u], __uint_as_float(zw[u].y << 16), a2);
      a3 = fmaf(xh[u], __uint_as_float(zw[u].y & 0xffff0000u), a3);
    }
  }
  for (; i < cdeg; i++) {
    int off = sc[hw][i];
    float x = exh[i];
    uint2 zw = *(const uint2*)(zpB + off);
    a0 = fmaf(x, __uint_as_float(zw.x << 16), a0);
    a1 = fmaf(x, __uint_as_float(zw.x & 0xffff0000u), a1);
    a2 = fmaf(x, __uint_as_float(zw.y << 16), a2);
    a3 = fmaf(x, __uint_as_float(zw.y & 0xffff0000u), a3);
  }
  for (; i < deg; i++) {  // beyond-CAP tail (not hit for this graph)
    int s = csr_src[rs + i];
    float2 l = el2[s];
    float x0 = __expf(lrelu(l.x + er0));
    float x1 = __expf(lrelu(l.y + er1));
    float x = head ? x1 : x0;
    uint2 zw = *(const uint2*)(zpB + ((size_t)s << 8));
    a0 = fmaf(x, __uint_as_float(zw.x << 16), a0);
    a1 = fmaf(x, __uint_as_float(zw.x & 0xffff0000u), a1);
    a2 = fmaf(x, __uint_as_float(zw.y << 16), a2);
    a3 = fmaf(x, __uint_as_float(zw.y & 0xffff0000u), a3);
  }

  if (valid) {
    float sp = head ? sp1 : sp0;
    float4 b4 = reinterpret_cast<const float4*>(bias)[l32];
    float o0, o1, o2, o3;
    if (deg == 0) { o0 = b4.x; o1 = b4.y; o2 = b4.z; o3 = b4.w; }
    else {
      o0 = a0 / sp + b4.x; o1 = a1 / sp + b4.y;
      o2 = a2 / sp + b4.z; o3 = a3 / sp + b4.w;
    }
    o0 = fmaxf(o0, 0.f); o1 = fmaxf(o1, 0.f);
    o2 = fmaxf(o2, 0.f); o3 = fmaxf(o3, 0.f);
    if (!fuse_out) {
      uint4 pk = make_uint4(pack_hilo(o0), pack_hilo(o1),
                            pack_hilo(o2), pack_hilo(o3));
      *(uint4*)&Hp[(size_t)node * 128 + 4 * l32] = pk;
    } else {
      float4 w4 = reinterpret_cast<const float4*>(ow)[l32];
      float d = o0 * w4.x + o1 * w4.y + o2 * w4.z + o3 * w4.w;
#pragma unroll
      for (int off = 16; off; off >>= 1) d += __shfl_xor(d, off, 64);
      if (l32 == 0) {
        z3[node] = d;
        el3[node] = d * oal[0];
        er3[node] = d * oar[0];
      }
    }
  }
}

// ---------------- output GAT layer: 32-lane group per node -----------------
__global__ __launch_bounds__(256) void agg3_kernel(
    const float* __restrict__ z3, const float* __restrict__ el3,
    const float* __restrict__ er3, const int* __restrict__ row_start,
    const int* __restrict__ csr_src, const float* __restrict__ b,
    float* __restrict__ out, int n) {
  int node = blockIdx.x * 8 + (threadIdx.x >> 5);
  int l32 = threadIdx.x & 31;
  if (node >= n) return;
  int rs = row_start[node];
  int deg = row_start[node + 1] - rs;
  float er = er3[node];
  float sp = 0.f, ap = 0.f;
  for (int i = l32; i < deg; i += 32) {
    int s = csr_src[rs + i];
    float ex = __expf(lrelu(el3[s] + er));
    sp += ex;
    ap = fmaf(ex, z3[s], ap);
  }
#pragma unroll
  for (int off = 16; off; off >>= 1) {
    sp += __shfl_xor(sp, off, 64);
    ap += __shfl_xor(ap, off, 64);
  }
  if (l32 == 0) out[node] = (deg == 0) ? b[0] : (ap / sp + b[0]);
}

// ---------------------------------------------------------------------------
extern "C" void kernel_launch(void* const* d_in, const int* in_sizes, int n_in,
                              void* d_out, int out_size, void* d_ws, size_t ws_size,
                              hipStream_t stream) {
  const float* feat     = (const float*)d_in[0];
  const int*   node_ids = (const int*)d_in[1];
  const int*   src      = (const int*)d_in[2];
  const int*   dst      = (const int*)d_in[3];
  const float* emb      = (const float*)d_in[4];
  const float* dense_w  = (const float*)d_in[5];
  const float* dense_b  = (const float*)d_in[6];
  const float* g1_w     = (const float*)d_in[7];
  const float* g1_al    = (const float*)d_in[8];
  const float* g1_ar    = (const float*)d_in[9];
  const float* g1_b     = (const float*)d_in[10];
  const float* g2_w     = (const float*)d_in[11];
  const float* g2_al    = (const float*)d_in[12];
  const float* g2_ar    = (const float*)d_in[13];
  const float* g2_b     = (const float*)d_in[14];
  const float* out_w    = (const float*)d_in[15];
  const float* out_al   = (const float*)d_in[16];
  const float* out_ar   = (const float*)d_in[17];
  const float* out_b    = (const float*)d_in[18];
  const int n = in_sizes[0] / 64;   // 50000
  const int e = in_sizes[2];        // 1600000

  const int ncb = (n + CBG - 1) / CBG;
  int lg = 0;
  while ((1 << lg) < n) lg++;
  const int sshift = lg > 3 ? lg - 3 : 0;

  char* ws = (char*)d_ws;
  size_t off = 0;
  auto alloc = [&](size_t bytes) -> void* {
    void* p = ws + off;
    off += (bytes + 255) & ~(size_t)255;
    return p;
  };
  uint32_t* Hp       = (uint32_t*)alloc((size_t)n * 128 * 4);
  size_t zp_bytes    = (size_t)n * 64 * 4;
  size_t tmp_bytes   = (size_t)ncb * CAPC * 4;
  uint32_t* zp       = (uint32_t*)alloc(zp_bytes > tmp_bytes ? zp_bytes : tmp_bytes);
  uint32_t* tmp      = zp;   // alias: tmp dead before zp first written (mfmm1)
  float2*   el2      = (float2*)alloc((size_t)n * 8);
  float2*   er2      = (float2*)alloc((size_t)n * 8);
  float*    z3       = (float*)alloc((size_t)n * 4);
  float*    el3      = (float*)alloc((size_t)n * 4);
  float*    er3      = (float*)alloc((size_t)n * 4);
  int*      scount   = (int*)alloc((size_t)ncb * 4);
  int*      row_start= (int*)alloc((size_t)(n + 1) * 4);
  int*      csr_src  = (int*)alloc((size_t)e * 4);
  short*    Wd_hi    = (short*)alloc(2048 * 8 * 2);
  short*    Wd_lo    = (short*)alloc(2048 * 8 * 2);
  short*    W1_hi    = (short*)alloc(2048 * 8 * 2);
  short*    W1_lo    = (short*)alloc(2048 * 8 * 2);
  short*    W2_hi    = (short*)alloc(2048 * 8 * 2);
  short*    W2_lo    = (short*)alloc(2048 * 8 * 2);
  // fallback-only buffers
  int*      cnt      = (int*)alloc((size_t)n * 4);
  int*      cursor   = (int*)alloc((size_t)n * 4);
  const int nblk     = (n + 1023) / 1024;
  int*      bsum     = (int*)alloc((size_t)nblk * 4);

  const int mmgrid = (n + 63) / 64;
  const int ngrid8 = (n + 7) / 8;

  // prep: W split+swizzle + scount zero (one launch)
  prep_kernel<<<25, 256, 0, stream>>>(dense_w, g1_w, g2_w,
                                      Wd_hi, Wd_lo, W1_hi, W1_lo, W2_hi, W2_lo,
                                      scount, ncb);

  if (n < 65536) {
    const int natile = (e + TILE - 1) / TILE;
    bucketA_kernel<<<natile, 256, 0, stream>>>(src, dst, scount, tmp, e, ncb);
    // fused: bucketB (first ncb blocks) + dense GEMM (remaining mmgrid blocks)
    mfmm0_bktB_kernel<<<ncb + mmgrid, 256, 0, stream>>>(
        tmp, scount, row_start, csr_src, ncb,
        Wd_hi, Wd_lo, dense_b, Hp, n, ncb, e, sshift, emb, node_ids, feat);
  } else {
    hipMemsetAsync(cnt, 0, (size_t)n * 4, stream);
    hipMemsetAsync(cursor, 0, (size_t)n * 4, stream);
    hist_kernel<<<2048, 256, 0, stream>>>(dst, cnt, e);
    scan1_kernel<<<nblk, 1024, 0, stream>>>(cnt, row_start, bsum, n);
    scan2_kernel<<<1, 64, 0, stream>>>(bsum, nblk);
    scan3_kernel<<<(n + 255) / 256, 256, 0, stream>>>(row_start, bsum, n, e);
    scatter_kernel<<<2048, 256, 0, stream>>>(src, dst, row_start, cursor, csr_src, e);
    mfmm0_bktB_kernel<<<mmgrid, 256, 0, stream>>>(
        tmp, scount, row_start, csr_src, 0,
        Wd_hi, Wd_lo, dense_b, Hp, n, ncb, e, sshift, emb, node_ids, feat);
  }

  // GAT layer 1
  mfmm1_kernel<<<mmgrid, 256, 0, stream>>>(Hp, W1_hi, W1_lo, zp, el2, er2,
                                           g1_al, g1_ar, n);
  agg12_kernel<<<ngrid8, 256, 0, stream>>>(zp, el2, er2, row_start, csr_src, g1_b, Hp,
                                           nullptr, nullptr, nullptr, nullptr, nullptr,
                                           nullptr, n, 0);
  // GAT layer 2 (+ fused output-layer z3/el3/er3)
  mfmm1_kernel<<<mmgrid, 256, 0, stream>>>(Hp, W2_hi, W2_lo, zp, el2, er2,
                                           g2_al, g2_ar, n);
  agg12_kernel<<<ngrid8, 256, 0, stream>>>(zp, el2, er2, row_start, csr_src, g2_b, nullptr,
                                           out_w, out_al, out_ar, z3, el3, er3, n, 1);
  // output GAT layer aggregation
  agg3_kernel<<<ngrid8, 256, 0, stream>>>(z3, el3, er3, row_start, csr_src, out_b,
                                          (float*)d_out, n);
}

// Round 14
// 218.982 us; speedup vs baseline: 1.0958x; 1.0958x over previous
//
#include <hip/hip_runtime.h>
#include <cfloat>
#include <cmath>

// ---------------------------------------------------------------------------
// UncertaintyGAT. Round-14: r12 agg12 restored (wave/node, 8-unroll, 28 VGPR,
// zero LDS conflicts -- r13's half-wave scheme lost via bank conflicts +
// occupancy). tmp no longer aliases zp (+9.6MB ws) which makes these fusions
// race-free (r11 lesson): fusedA = bucketA || dense-GEMM, fusedB = bucketB ||
// layer-1 z-GEMM. 7 dispatches. agg12 inter-phase barrier dropped (per-wave
// LDS only). agg12 is at its structural floor: FETCH/2.9TB/s, bytes set by
// cache geometry on a random graph (r10), bf16 is the precision floor.
// ---------------------------------------------------------------------------

#define CBG 256
#define CAPC 12288
#define TILE 4096
#define BIMG 10240

typedef __attribute__((ext_vector_type(8))) short short8v;
typedef __attribute__((ext_vector_type(4))) float f32x4;

__device__ __forceinline__ float lrelu(float x) { return x > 0.f ? x : 0.2f * x; }

__device__ __forceinline__ uint32_t bf16_rne(float f) {
  uint32_t u = __float_as_uint(f);
  return (u + 0x7fffu + ((u >> 16) & 1u)) >> 16;
}
__device__ __forceinline__ uint32_t pack_hilo(float v) {
  uint32_t h = bf16_rne(v);
  float r = v - __uint_as_float(h << 16);
  return (h << 16) | bf16_rne(r);
}

// ---------------- prep: W split+swizzle (blocks 0..23) + scount zero -------
__global__ __launch_bounds__(256) void prep_kernel(
    const float* __restrict__ W0, const float* __restrict__ W1,
    const float* __restrict__ W2, short* __restrict__ Whi0,
    short* __restrict__ Wlo0, short* __restrict__ Whi1, short* __restrict__ Wlo1,
    short* __restrict__ Whi2, short* __restrict__ Wlo2,
    int* __restrict__ scount, int ncb) {
  if (blockIdx.x >= 24) {
    for (int i = threadIdx.x; i < ncb; i += 256) scount[i] = 0;
    return;
  }
  int which = blockIdx.x >> 3;
  const float* W = which == 0 ? W0 : (which == 1 ? W1 : W2);
  short* Whi = which == 0 ? Whi0 : (which == 1 ? Whi1 : Whi2);
  short* Wlo = which == 0 ? Wlo0 : (which == 1 ? Wlo1 : Wlo2);
  int fid = (blockIdx.x & 7) * 256 + threadIdx.x;  // 0..2047
  int lane = fid & 63;
  int cq = fid >> 6;
  int q = cq >> 3, c = cq & 7;
  int col = c * 16 + (lane & 15);
  int k0 = q * 32 + (lane >> 4) * 8;
#pragma unroll
  for (int j = 0; j < 8; j++) {
    float v = W[(k0 + j) * 128 + col];
    uint32_t h = bf16_rne(v);
    float r = v - __uint_as_float(h << 16);
    Whi[fid * 8 + j] = (short)h;
    Wlo[fid * 8 + j] = (short)bf16_rne(r);
  }
}

// ---------------- bucketA body (uses caller LDS; 19.5KB) ----------------
__device__ __forceinline__ void bucketA_body(
    int blk, char* smem, const int* __restrict__ src, const int* __restrict__ dst,
    int* __restrict__ scount, uint32_t* __restrict__ tmp, int e, int ncb) {
  int* cnt = (int*)smem;                 // 256
  int* lscan = cnt + 256;                // 256
  int* gbase = lscan + 256;              // 256
  uint32_t* image = (uint32_t*)(smem + 3072);  // TILE
  const int t = threadIdx.x;
  const int e0 = blk * TILE;
  const int ne = min(TILE, e - e0);

  for (int i = t; i < 256; i += 256) cnt[i] = 0;
  __syncthreads();
  for (int i = t; i < ne; i += 256) atomicAdd(&cnt[dst[e0 + i] >> 8], 1);
  __syncthreads();
  if (t < 64) {
    int carry = 0;
    for (int base = 0; base < ncb; base += 64) {
      int idx = base + t;
      int c = (idx < ncb) ? cnt[idx] : 0;
      int v = c;
#pragma unroll
      for (int off = 1; off < 64; off <<= 1) {
        int u = __shfl_up(v, off, 64);
        if (t >= off) v += u;
      }
      if (idx < ncb) lscan[idx] = carry + v - c;
      carry += __shfl(v, 63, 64);
    }
  }
  __syncthreads();
  for (int b = t; b < ncb; b += 256)
    gbase[b] = (cnt[b] > 0) ? atomicAdd(&scount[b], cnt[b]) : 0;
  __syncthreads();
  for (int b = t; b < ncb; b += 256) cnt[b] = 0;
  __syncthreads();
  for (int i = t; i < ne; i += 256) {
    int d = dst[e0 + i], s = src[e0 + i];
    int b = d >> 8;
    int r = atomicAdd(&cnt[b], 1);
    image[lscan[b] + r] =
        (uint32_t)s | ((uint32_t)(d & 255) << 16) | ((uint32_t)b << 24);
  }
  __syncthreads();
  for (int j = t; j < ne; j += 256) {
    uint32_t w = image[j];
    int b = w >> 24;
    int pos = gbase[b] + (j - lscan[b]);
    if (pos < CAPC) tmp[(size_t)b * CAPC + pos] = w & 0xFFFFFFu;
  }
}

// ---------------- bucketB body: key = dst_local*8 + src_block --------------
__device__ __forceinline__ void bucketB_body(
    int b, char* smem, const uint32_t* __restrict__ tmp,
    const int* __restrict__ scount, int* __restrict__ row_start,
    int* __restrict__ csr_src, int n, int ncb, int e, int sshift) {
  int* cnt2 = (int*)smem;                      // 2048 (hist -> cursor)
  int* wsum = cnt2 + 2048;                     // 4
  int* s_base = wsum + 4;                      // 1
  uint32_t* image = (uint32_t*)(smem + 8224);  // BIMG
  const int t = threadIdx.x, lane = t & 63, wid = t >> 6;

  if (t < 64) {
    int part = 0;
    for (int idx = lane; idx < b; idx += 64) part += scount[idx];
#pragma unroll
    for (int off = 32; off; off >>= 1) part += __shfl_xor(part, off, 64);
    if (lane == 0) *s_base = part;
  }
#pragma unroll
  for (int j = 0; j < 8; j++) cnt2[t * 8 + j] = 0;
  __syncthreads();
  const int total = min(scount[b], CAPC);
  const int base = *s_base;
  const uint32_t* strm = tmp + (size_t)b * CAPC;

  for (int i = t; i < total; i += 256) {
    uint32_t w = strm[i];
    int key = (((w >> 16) & 255) << 3) + ((w & 0xFFFFu) >> sshift);
    atomicAdd(&cnt2[key], 1);
  }
  __syncthreads();
  int c8[8];
  int run = 0;
#pragma unroll
  for (int j = 0; j < 8; j++) { int x = cnt2[t * 8 + j]; c8[j] = run; run += x; }
  int c = run, v = c;
#pragma unroll
  for (int off = 1; off < 64; off <<= 1) {
    int u = __shfl_up(v, off, 64);
    if (lane >= off) v += u;
  }
  if (lane == 63) wsum[wid] = v;
  __syncthreads();
  if (t == 0) {
    int acc = 0;
#pragma unroll
    for (int w = 0; w < 4; w++) { int x = wsum[w]; wsum[w] = acc; acc += x; }
  }
  __syncthreads();
  int ex = wsum[wid] + v - c;
#pragma unroll
  for (int j = 0; j < 8; j++) cnt2[t * 8 + j] = ex + c8[j];
  int d = b * CBG + t;
  if (d < n) row_start[d] = base + ex;
  if (b == 0 && t == 0) row_start[n] = e;
  __syncthreads();
  for (int i = t; i < total; i += 256) {
    uint32_t w = strm[i];
    uint32_t s = w & 0xFFFFu;
    int key = (((w >> 16) & 255) << 3) + (s >> sshift);
    int pos = atomicAdd(&cnt2[key], 1);
    if (pos < BIMG) image[pos] = s;
    else csr_src[base + pos] = (int)s;
  }
  __syncthreads();
  const int lim = total < BIMG ? total : BIMG;
  for (int j = t; j < lim; j += 256) csr_src[base + j] = (int)image[j];
}

// ---------------- MFMA GEMM body (uses caller LDS; 34.8KB) ----------------
template <int MODE>
__device__ __forceinline__ void mfmm_body(
    int bid, char* smem,
    const uint32_t* __restrict__ Xp, const short* __restrict__ Whi,
    const short* __restrict__ Wlo, const float* __restrict__ bias,
    uint32_t* __restrict__ Hp, uint32_t* __restrict__ zp,
    float2* __restrict__ el2, float2* __restrict__ er2,
    const float* __restrict__ al, const float* __restrict__ ar, int n,
    const float* __restrict__ emb, const int* __restrict__ ids,
    const float* __restrict__ feat) {
  short* Ahi = (short*)smem;
  short* Alo = Ahi + 64 * 136;
  const int t = threadIdx.x;
  const int nb = bid * 64;

  for (int idx = t; idx < 64 * 32; idx += 256) {
    int nl = idx >> 5, k4 = (idx & 31) << 2;
    int node = nb + nl;
    uint32_t h01 = 0, h23 = 0, l01 = 0, l23 = 0;
    if (node < n) {
      if (MODE == 1) {
        uint4 w = *(const uint4*)&Xp[(size_t)node * 128 + k4];
        h01 = (w.x >> 16) | (w.y & 0xffff0000u);
        l01 = (w.x & 0xffffu) | (w.y << 16);
        h23 = (w.z >> 16) | (w.w & 0xffff0000u);
        l23 = (w.z & 0xffffu) | (w.w << 16);
      } else {
        float4 v;
        if (k4 < 64) v = *(const float4*)&emb[(size_t)ids[node] * 64 + k4];
        else         v = *(const float4*)&feat[(size_t)node * 64 + (k4 - 64)];
        uint32_t a0 = bf16_rne(v.x), a1 = bf16_rne(v.y);
        uint32_t a2 = bf16_rne(v.z), a3 = bf16_rne(v.w);
        h01 = a0 | (a1 << 16);
        h23 = a2 | (a3 << 16);
        l01 = bf16_rne(v.x - __uint_as_float(a0 << 16)) |
              (bf16_rne(v.y - __uint_as_float(a1 << 16)) << 16);
        l23 = bf16_rne(v.z - __uint_as_float(a2 << 16)) |
              (bf16_rne(v.w - __uint_as_float(a3 << 16)) << 16);
      }
    }
    *(uint2*)&Ahi[nl * 136 + k4] = make_uint2(h01, h23);
    *(uint2*)&Alo[nl * 136 + k4] = make_uint2(l01, l23);
  }
  __syncthreads();

  const int lane = t & 63, wv = t >> 6;
  const int r16 = lane & 15, g = lane >> 4;
  const int arow = (wv * 16 + r16) * 136;

  f32x4 acc[8];
#pragma unroll
  for (int c = 0; c < 8; c++) acc[c] = (f32x4){0.f, 0.f, 0.f, 0.f};

#pragma unroll
  for (int q = 0; q < 4; q++) {
    int ka = q * 32 + g * 8;
    short8v ahi = *(const short8v*)&Ahi[arow + ka];
    short8v alo = *(const short8v*)&Alo[arow + ka];
#pragma unroll
    for (int c = 0; c < 8; c++) {
      short8v bhi = *(const short8v*)&Whi[(((q * 8 + c) * 64) + lane) * 8];
      short8v blo = *(const short8v*)&Wlo[(((q * 8 + c) * 64) + lane) * 8];
      acc[c] = __builtin_amdgcn_mfma_f32_16x16x32_bf16(ahi, bhi, acc[c], 0, 0, 0);
      acc[c] = __builtin_amdgcn_mfma_f32_16x16x32_bf16(ahi, blo, acc[c], 0, 0, 0);
      acc[c] = __builtin_amdgcn_mfma_f32_16x16x32_bf16(alo, bhi, acc[c], 0, 0, 0);
    }
  }

  const int node_base = nb + wv * 16;
  if (MODE == 0) {
#pragma unroll
    for (int c = 0; c < 8; c++) {
      int col = c * 16 + r16;
      float bv = bias[col];
#pragma unroll
      for (int r = 0; r < 4; r++) {
        int node = node_base + g * 4 + r;
        if (node < n) {
          float v = fmaxf(acc[c][r] + bv, 0.f);
          Hp[(size_t)node * 128 + col] = pack_hilo(v);
        }
      }
    }
  } else {
    float p0l[4] = {0, 0, 0, 0}, p1l[4] = {0, 0, 0, 0};
    float p0r[4] = {0, 0, 0, 0}, p1r[4] = {0, 0, 0, 0};
#pragma unroll
    for (int c = 0; c < 8; c++) {
      int col = c * 16 + r16;
      float av = al[col], rv = ar[col];
#pragma unroll
      for (int r = 0; r < 4; r++) {
        if (c < 4) { p0l[r] = fmaf(acc[c][r], av, p0l[r]); p0r[r] = fmaf(acc[c][r], rv, p0r[r]); }
        else       { p1l[r] = fmaf(acc[c][r], av, p1l[r]); p1r[r] = fmaf(acc[c][r], rv, p1r[r]); }
      }
    }
#pragma unroll
    for (int c = 0; c < 8; c++) {
#pragma unroll
      for (int r = 0; r < 4; r++) {
        float other = __shfl_xor(acc[c][r], 1, 64);
        int node = node_base + g * 4 + r;
        if (!(lane & 1) && node < n) {
          uint32_t w = bf16_rne(acc[c][r]) | (bf16_rne(other) << 16);
          zp[(size_t)node * 64 + c * 8 + (r16 >> 1)] = w;
        }
      }
    }
#pragma unroll
    for (int off = 1; off < 16; off <<= 1) {
#pragma unroll
      for (int r = 0; r < 4; r++) {
        p0l[r] += __shfl_xor(p0l[r], off, 64);
        p1l[r] += __shfl_xor(p1l[r], off, 64);
        p0r[r] += __shfl_xor(p0r[r], off, 64);
        p1r[r] += __shfl_xor(p1r[r], off, 64);
      }
    }
    if (r16 == 0) {
#pragma unroll
      for (int r = 0; r < 4; r++) {
        int node = node_base + g * 4 + r;
        if (node < n) {
          el2[node] = make_float2(p0l[r], p1l[r]);
          er2[node] = make_float2(p0r[r], p1r[r]);
        }
      }
    }
  }
}

// ---- fusedA: bucketA (blocks [0,nA)) || dense GEMM. Disjoint buffers:
// bucketA{src,dst,scount,tmp} vs mfmm0{emb,ids,feat,Wd,Hp}. tmp is a real
// allocation now (no zp alias) -> no r11-style race. ----
__global__ __launch_bounds__(256) void fusedA_kernel(
    const int* __restrict__ src, const int* __restrict__ dst,
    int* __restrict__ scount, uint32_t* __restrict__ tmp, int e, int ncb, int nA,
    const short* __restrict__ Whi, const short* __restrict__ Wlo,
    const float* __restrict__ bias, uint32_t* __restrict__ Hp, int n,
    const float* __restrict__ emb, const int* __restrict__ ids,
    const float* __restrict__ feat) {
  __shared__ __align__(16) char smem[34816];
  if ((int)blockIdx.x < nA) {
    bucketA_body(blockIdx.x, smem, src, dst, scount, tmp, e, ncb);
  } else {
    mfmm_body<0>(blockIdx.x - nA, smem, nullptr, Whi, Wlo, bias, Hp,
                 nullptr, nullptr, nullptr, nullptr, nullptr, n, emb, ids, feat);
  }
}

// ---- fusedB: bucketB (blocks [0,ncbB)) || layer-1 z-GEMM. Disjoint:
// bucketB{tmp,scount,row_start,csr_src} vs mfmm1{Hp,W1,zp,el2,er2}. ----
__global__ __launch_bounds__(256) void fusedB_kernel(
    const uint32_t* __restrict__ tmp, const int* __restrict__ scount,
    int* __restrict__ row_start, int* __restrict__ csr_src, int ncbB,
    int n, int ncb, int e, int sshift,
    const uint32_t* __restrict__ Xp, const short* __restrict__ Whi,
    const short* __restrict__ Wlo, uint32_t* __restrict__ zp,
    float2* __restrict__ el2, float2* __restrict__ er2,
    const float* __restrict__ al, const float* __restrict__ ar) {
  __shared__ __align__(16) char smem[49200];
  if ((int)blockIdx.x < ncbB) {
    bucketB_body(blockIdx.x, smem, tmp, scount, row_start, csr_src, n, ncb, e,
                 sshift);
  } else {
    mfmm_body<1>(blockIdx.x - ncbB, smem, Xp, Whi, Wlo, nullptr, nullptr, zp,
                 el2, er2, al, ar, n, nullptr, nullptr, nullptr);
  }
}

__global__ __launch_bounds__(256) void mfmm1_kernel(
    const uint32_t* __restrict__ Xp, const short* __restrict__ Whi,
    const short* __restrict__ Wlo, uint32_t* __restrict__ zp,
    float2* __restrict__ el2, float2* __restrict__ er2,
    const float* __restrict__ al, const float* __restrict__ ar, int n) {
  __shared__ __align__(16) char smem[34816];
  mfmm_body<1>(blockIdx.x, smem, Xp, Whi, Wlo, nullptr, nullptr, zp, el2, er2,
               al, ar, n, nullptr, nullptr, nullptr);
}

// ---------------- fallback path (n >= 65536) ----------------
__global__ void hist_kernel(const int* __restrict__ dst, int* __restrict__ cnt, int e) {
  for (int i = blockIdx.x * blockDim.x + threadIdx.x; i < e; i += gridDim.x * blockDim.x)
    atomicAdd(&cnt[dst[i]], 1);
}
__global__ void scatter_kernel(const int* __restrict__ src, const int* __restrict__ dst,
                               const int* __restrict__ row_start, int* __restrict__ cursor,
                               int* __restrict__ csr_src, int e) {
  for (int i = blockIdx.x * blockDim.x + threadIdx.x; i < e; i += gridDim.x * blockDim.x) {
    int d = dst[i];
    int pos = atomicAdd(&cursor[d], 1);
    csr_src[row_start[d] + pos] = src[i];
  }
}
__global__ __launch_bounds__(1024) void scan1_kernel(const int* __restrict__ cnt,
                                                     int* __restrict__ row_start,
                                                     int* __restrict__ bsum, int n) {
  __shared__ int wsum[16];
  const int t = threadIdx.x, lane = t & 63, wid = t >> 6;
  int i = blockIdx.x * 1024 + t;
  int c = (i < n) ? cnt[i] : 0;
  int v = c;
#pragma unroll
  for (int off = 1; off < 64; off <<= 1) {
    int u = __shfl_up(v, off, 64);
    if (lane >= off) v += u;
  }
  if (lane == 63) wsum[wid] = v;
  __syncthreads();
  if (t == 0) {
    int acc = 0;
#pragma unroll
    for (int w = 0; w < 16; w++) { int x = wsum[w]; wsum[w] = acc; acc += x; }
    bsum[blockIdx.x] = acc;
  }
  __syncthreads();
  if (i < n) row_start[i] = wsum[wid] + v - c;
}
__global__ __launch_bounds__(64) void scan2_kernel(int* __restrict__ bsum, int nb) {
  const int lane = threadIdx.x;
  int carry = 0;
  for (int base = 0; base < nb; base += 64) {
    int idx = base + lane;
    int c = (idx < nb) ? bsum[idx] : 0;
    int v = c;
#pragma unroll
    for (int off = 1; off < 64; off <<= 1) {
      int u = __shfl_up(v, off, 64);
      if (lane >= off) v += u;
    }
    if (idx < nb) bsum[idx] = carry + v - c;
    carry += __shfl(v, 63, 64);
  }
}
__global__ void scan3_kernel(int* __restrict__ row_start, const int* __restrict__ bsum,
                             int n, int e) {
  int i = blockIdx.x * blockDim.x + threadIdx.x;
  if (i < n) row_start[i] += bsum[i >> 10];
  if (i == 0) row_start[n] = e;
}

// ---------------- GAT aggregation (wave per dst node) -- r12 version -------
// phase-1: full-wave float2 el2 gather; stores byte offsets (s<<8) and
// per-head split exp tables. phase-2: 8-unroll, one-add addressing,
// broadcast per-head x read. Per-wave LDS slices -> no inter-phase barrier.
#define CAP 256
__global__ __launch_bounds__(256) void agg12_kernel(
    const uint32_t* __restrict__ zp, const float2* __restrict__ el2,
    const float2* __restrict__ er2, const int* __restrict__ row_start,
    const int* __restrict__ csr_src, const float* __restrict__ bias,
    uint32_t* __restrict__ Hp,
    const float* __restrict__ ow, const float* __restrict__ oal,
    const float* __restrict__ oar, float* __restrict__ z3,
    float* __restrict__ el3, float* __restrict__ er3, int n, int fuse_out) {
  __shared__ float ecf[4][2][CAP];
  __shared__ int sc[4][CAP];
  const int w = threadIdx.x >> 6, lane = threadIdx.x & 63;
  const int node = blockIdx.x * 4 + w;
  const bool valid = node < n;
  int rs = 0, deg = 0;
  float er0 = 0.f, er1 = 0.f;
  if (valid) {
    rs = row_start[node];
    deg = row_start[node + 1] - rs;
    float2 e2 = er2[node];
    er0 = e2.x; er1 = e2.y;
  }
  const int cdeg = deg < CAP ? deg : CAP;

  float sp0 = 0.f, sp1 = 0.f;
  for (int i = lane; i < deg; i += 64) {
    int s = csr_src[rs + i];
    float2 l = el2[s];
    float x0 = __expf(lrelu(l.x + er0));
    float x1 = __expf(lrelu(l.y + er1));
    if (i < CAP) { sc[w][i] = s << 8; ecf[w][0][i] = x0; ecf[w][1][i] = x1; }
    sp0 += x0; sp1 += x1;
  }
#pragma unroll
  for (int off = 32; off; off >>= 1) {
    sp0 += __shfl_xor(sp0, off, 64);
    sp1 += __shfl_xor(sp1, off, 64);
  }
  // no __syncthreads(): sc/ecf slices are per-wave (write+read by same wave)

  const float* exh = ecf[w][lane >> 5];
  const char* zpB = (const char*)zp + (size_t)lane * 4;
  float ae = 0.f, ao = 0.f;
  int i = 0;
  for (; i + 8 <= cdeg; i += 8) {
    uint32_t zw[8];
    float xh[8];
#pragma unroll
    for (int u = 0; u < 8; u++) {
      int off = sc[w][i + u];
      xh[u] = exh[i + u];
      zw[u] = *(const uint32_t*)(zpB + off);
    }
#pragma unroll
    for (int u = 0; u < 8; u++) {
      ae = fmaf(xh[u], __uint_as_float(zw[u] << 16), ae);
      ao = fmaf(xh[u], __uint_as_float(zw[u] & 0xffff0000u), ao);
    }
  }
  for (; i < cdeg; i++) {
    int off = sc[w][i];
    float x = exh[i];
    uint32_t zw = *(const uint32_t*)(zpB + off);
    ae = fmaf(x, __uint_as_float(zw << 16), ae);
    ao = fmaf(x, __uint_as_float(zw & 0xffff0000u), ao);
  }
  for (; i < deg; i++) {  // beyond-CAP tail (not hit for this graph)
    int s = csr_src[rs + i];
    float2 l = el2[s];
    float x0 = __expf(lrelu(l.x + er0));
    float x1 = __expf(lrelu(l.y + er1));
    float x = (lane < 32) ? x0 : x1;
    uint32_t zw = *(const uint32_t*)(zpB + ((size_t)s << 8));
    ae = fmaf(x, __uint_as_float(zw << 16), ae);
    ao = fmaf(x, __uint_as_float(zw & 0xffff0000u), ao);
  }

  if (valid) {
    float sp = (lane < 32) ? sp0 : sp1;
    float2 b2 = reinterpret_cast<const float2*>(bias)[lane];
    float oe, oo;
    if (deg == 0) { oe = b2.x; oo = b2.y; }
    else { oe = ae / sp + b2.x; oo = ao / sp + b2.y; }
    oe = fmaxf(oe, 0.f);
    oo = fmaxf(oo, 0.f);
    if (!fuse_out) {
      *(uint2*)&Hp[(size_t)node * 128 + 2 * lane] =
          make_uint2(pack_hilo(oe), pack_hilo(oo));
    } else {
      float2 w2 = reinterpret_cast<const float2*>(ow)[lane];
      float d = oe * w2.x + oo * w2.y;
#pragma unroll
      for (int off = 32; off; off >>= 1) d += __shfl_xor(d, off, 64);
      if (lane == 0) {
        z3[node] = d;
        el3[node] = d * oal[0];
        er3[node] = d * oar[0];
      }
    }
  }
}

// ---------------- output GAT layer: 32-lane group per node -----------------
__global__ __launch_bounds__(256) void agg3_kernel(
    const float* __restrict__ z3, const float* __restrict__ el3,
    const float* __restrict__ er3, const int* __restrict__ row_start,
    const int* __restrict__ csr_src, const float* __restrict__ b,
    float* __restrict__ out, int n) {
  int node = blockIdx.x * 8 + (threadIdx.x >> 5);
  int l32 = threadIdx.x & 31;
  if (node >= n) return;
  int rs = row_start[node];
  int deg = row_start[node + 1] - rs;
  float er = er3[node];
  float sp = 0.f, ap = 0.f;
  for (int i = l32; i < deg; i += 32) {
    int s = csr_src[rs + i];
    float ex = __expf(lrelu(el3[s] + er));
    sp += ex;
    ap = fmaf(ex, z3[s], ap);
  }
#pragma unroll
  for (int off = 16; off; off >>= 1) {
    sp += __shfl_xor(sp, off, 64);
    ap += __shfl_xor(ap, off, 64);
  }
  if (l32 == 0) out[node] = (deg == 0) ? b[0] : (ap / sp + b[0]);
}

// ---------------------------------------------------------------------------
extern "C" void kernel_launch(void* const* d_in, const int* in_sizes, int n_in,
                              void* d_out, int out_size, void* d_ws, size_t ws_size,
                              hipStream_t stream) {
  const float* feat     = (const float*)d_in[0];
  const int*   node_ids = (const int*)d_in[1];
  const int*   src      = (const int*)d_in[2];
  const int*   dst      = (const int*)d_in[3];
  const float* emb      = (const float*)d_in[4];
  const float* dense_w  = (const float*)d_in[5];
  const float* dense_b  = (const float*)d_in[6];
  const float* g1_w     = (const float*)d_in[7];
  const float* g1_al    = (const float*)d_in[8];
  const float* g1_ar    = (const float*)d_in[9];
  const float* g1_b     = (const float*)d_in[10];
  const float* g2_w     = (const float*)d_in[11];
  const float* g2_al    = (const float*)d_in[12];
  const float* g2_ar    = (const float*)d_in[13];
  const float* g2_b     = (const float*)d_in[14];
  const float* out_w    = (const float*)d_in[15];
  const float* out_al   = (const float*)d_in[16];
  const float* out_ar   = (const float*)d_in[17];
  const float* out_b    = (const float*)d_in[18];
  const int n = in_sizes[0] / 64;   // 50000
  const int e = in_sizes[2];        // 1600000

  const int ncb = (n + CBG - 1) / CBG;
  int lg = 0;
  while ((1 << lg) < n) lg++;
  const int sshift = lg > 3 ? lg - 3 : 0;

  char* ws = (char*)d_ws;
  size_t off = 0;
  auto alloc = [&](size_t bytes) -> void* {
    void* p = ws + off;
    off += (bytes + 255) & ~(size_t)255;
    return p;
  };
  uint32_t* Hp       = (uint32_t*)alloc((size_t)n * 128 * 4);
  uint32_t* zp       = (uint32_t*)alloc((size_t)n * 64 * 4);
  uint32_t* tmp      = (uint32_t*)alloc((size_t)ncb * CAPC * 4);  // no alias
  float2*   el2      = (float2*)alloc((size_t)n * 8);
  float2*   er2      = (float2*)alloc((size_t)n * 8);
  float*    z3       = (float*)alloc((size_t)n * 4);
  float*    el3      = (float*)alloc((size_t)n * 4);
  float*    er3      = (float*)alloc((size_t)n * 4);
  int*      scount   = (int*)alloc((size_t)ncb * 4);
  int*      row_start= (int*)alloc((size_t)(n + 1) * 4);
  int*      csr_src  = (int*)alloc((size_t)e * 4);
  short*    Wd_hi    = (short*)alloc(2048 * 8 * 2);
  short*    Wd_lo    = (short*)alloc(2048 * 8 * 2);
  short*    W1_hi    = (short*)alloc(2048 * 8 * 2);
  short*    W1_lo    = (short*)alloc(2048 * 8 * 2);
  short*    W2_hi    = (short*)alloc(2048 * 8 * 2);
  short*    W2_lo    = (short*)alloc(2048 * 8 * 2);
  // fallback-only buffers
  int*      cnt      = (int*)alloc((size_t)n * 4);
  int*      cursor   = (int*)alloc((size_t)n * 4);
  const int nblk     = (n + 1023) / 1024;
  int*      bsum     = (int*)alloc((size_t)nblk * 4);

  const int mmgrid = (n + 63) / 64;
  const int ngrid4 = (n + 3) / 4;
  const int ngrid8 = (n + 7) / 8;

  // prep: W split+swizzle + scount zero
  prep_kernel<<<25, 256, 0, stream>>>(dense_w, g1_w, g2_w,
                                      Wd_hi, Wd_lo, W1_hi, W1_lo, W2_hi, W2_lo,
                                      scount, ncb);

  if (n < 65536) {
    const int natile = (e + TILE - 1) / TILE;
    // fusedA: bucketA || dense GEMM (both depend only on prep; disjoint bufs)
    fusedA_kernel<<<natile + mmgrid, 256, 0, stream>>>(
        src, dst, scount, tmp, e, ncb, natile,
        Wd_hi, Wd_lo, dense_b, Hp, n, emb, node_ids, feat);
    // fusedB: bucketB || layer-1 z-GEMM (both depend on fusedA; disjoint bufs)
    fusedB_kernel<<<ncb + mmgrid, 256, 0, stream>>>(
        tmp, scount, row_start, csr_src, ncb, n, ncb, e, sshift,
        Hp, W1_hi, W1_lo, zp, el2, er2, g1_al, g1_ar);
  } else {
    hipMemsetAsync(cnt, 0, (size_t)n * 4, stream);
    hipMemsetAsync(cursor, 0, (size_t)n * 4, stream);
    hist_kernel<<<2048, 256, 0, stream>>>(dst, cnt, e);
    scan1_kernel<<<nblk, 1024, 0, stream>>>(cnt, row_start, bsum, n);
    scan2_kernel<<<1, 64, 0, stream>>>(bsum, nblk);
    scan3_kernel<<<(n + 255) / 256, 256, 0, stream>>>(row_start, bsum, n, e);
    scatter_kernel<<<2048, 256, 0, stream>>>(src, dst, row_start, cursor, csr_src, e);
    fusedA_kernel<<<mmgrid, 256, 0, stream>>>(
        src, dst, scount, tmp, e, ncb, 0,
        Wd_hi, Wd_lo, dense_b, Hp, n, emb, node_ids, feat);
    fusedB_kernel<<<mmgrid, 256, 0, stream>>>(
        tmp, scount, row_start, csr_src, 0, n, ncb, e, sshift,
        Hp, W1_hi, W1_lo, zp, el2, er2, g1_al, g1_ar);
  }

  // GAT layer 1 aggregation
  agg12_kernel<<<ngrid4, 256, 0, stream>>>(zp, el2, er2, row_start, csr_src, g1_b, Hp,
                                           nullptr, nullptr, nullptr, nullptr, nullptr,
                                           nullptr, n, 0);
  // GAT layer 2 z-GEMM + aggregation (fused output-layer z3/el3/er3)
  mfmm1_kernel<<<mmgrid, 256, 0, stream>>>(Hp, W2_hi, W2_lo, zp, el2, er2,
                                           g2_al, g2_ar, n);
  agg12_kernel<<<ngrid4, 256, 0, stream>>>(zp, el2, er2, row_start, csr_src, g2_b, nullptr,
                                           out_w, out_al, out_ar, z3, el3, er3, n, 1);
  // output GAT layer aggregation
  agg3_kernel<<<ngrid8, 256, 0, stream>>>(z3, el3, er3, row_start, csr_src, out_b,
                                          (float*)d_out, n);
}

// Round 16
// 214.550 us; speedup vs baseline: 1.1184x; 1.0207x over previous
//
#include <hip/hip_runtime.h>
#include <cfloat>
#include <cmath>

// ---------------------------------------------------------------------------
// UncertaintyGAT. Round-16 = round-15 with the call-site arity fix (layer-1
// agg12 call was missing one nullptr after the z3/el3/er3 -> zel/er3 merge).
//  - bucketB direct scatter (8.2KB LDS): each block writes its own contiguous
//    ~32KB csr window -> no r4-style write amplification; fusedB LDS union
//    34.8KB -> z-GEMM co-residency 4 blocks/CU.
//  - (z3, el3) packed as float2 -> agg3 does ONE 8B random gather per edge.
//  agg12 untouched (r14 operating point: wave/node, 8-unroll, 28 VGPR,
//  0 conflicts -- 55us fetch-path bound, escape routes disproved r7/r10/r12/r13).
// ---------------------------------------------------------------------------

#define CBG 256
#define CAPC 12288
#define TILE 4096

typedef __attribute__((ext_vector_type(8))) short short8v;
typedef __attribute__((ext_vector_type(4))) float f32x4;

__device__ __forceinline__ float lrelu(float x) { return x > 0.f ? x : 0.2f * x; }

__device__ __forceinline__ uint32_t bf16_rne(float f) {
  uint32_t u = __float_as_uint(f);
  return (u + 0x7fffu + ((u >> 16) & 1u)) >> 16;
}
__device__ __forceinline__ uint32_t pack_hilo(float v) {
  uint32_t h = bf16_rne(v);
  float r = v - __uint_as_float(h << 16);
  return (h << 16) | bf16_rne(r);
}

// ---------------- prep: W split+swizzle (blocks 0..23) + scount zero -------
__global__ __launch_bounds__(256) void prep_kernel(
    const float* __restrict__ W0, const float* __restrict__ W1,
    const float* __restrict__ W2, short* __restrict__ Whi0,
    short* __restrict__ Wlo0, short* __restrict__ Whi1, short* __restrict__ Wlo1,
    short* __restrict__ Whi2, short* __restrict__ Wlo2,
    int* __restrict__ scount, int ncb) {
  if (blockIdx.x >= 24) {
    for (int i = threadIdx.x; i < ncb; i += 256) scount[i] = 0;
    return;
  }
  int which = blockIdx.x >> 3;
  const float* W = which == 0 ? W0 : (which == 1 ? W1 : W2);
  short* Whi = which == 0 ? Whi0 : (which == 1 ? Whi1 : Whi2);
  short* Wlo = which == 0 ? Wlo0 : (which == 1 ? Wlo1 : Wlo2);
  int fid = (blockIdx.x & 7) * 256 + threadIdx.x;  // 0..2047
  int lane = fid & 63;
  int cq = fid >> 6;
  int q = cq >> 3, c = cq & 7;
  int col = c * 16 + (lane & 15);
  int k0 = q * 32 + (lane >> 4) * 8;
#pragma unroll
  for (int j = 0; j < 8; j++) {
    float v = W[(k0 + j) * 128 + col];
    uint32_t h = bf16_rne(v);
    float r = v - __uint_as_float(h << 16);
    Whi[fid * 8 + j] = (short)h;
    Wlo[fid * 8 + j] = (short)bf16_rne(r);
  }
}

// ---------------- bucketA body (uses caller LDS; 19.5KB) ----------------
__device__ __forceinline__ void bucketA_body(
    int blk, char* smem, const int* __restrict__ src, const int* __restrict__ dst,
    int* __restrict__ scount, uint32_t* __restrict__ tmp, int e, int ncb) {
  int* cnt = (int*)smem;                 // 256
  int* lscan = cnt + 256;                // 256
  int* gbase = lscan + 256;              // 256
  uint32_t* image = (uint32_t*)(smem + 3072);  // TILE
  const int t = threadIdx.x;
  const int e0 = blk * TILE;
  const int ne = min(TILE, e - e0);

  for (int i = t; i < 256; i += 256) cnt[i] = 0;
  __syncthreads();
  for (int i = t; i < ne; i += 256) atomicAdd(&cnt[dst[e0 + i] >> 8], 1);
  __syncthreads();
  if (t < 64) {
    int carry = 0;
    for (int base = 0; base < ncb; base += 64) {
      int idx = base + t;
      int c = (idx < ncb) ? cnt[idx] : 0;
      int v = c;
#pragma unroll
      for (int off = 1; off < 64; off <<= 1) {
        int u = __shfl_up(v, off, 64);
        if (t >= off) v += u;
      }
      if (idx < ncb) lscan[idx] = carry + v - c;
      carry += __shfl(v, 63, 64);
    }
  }
  __syncthreads();
  for (int b = t; b < ncb; b += 256)
    gbase[b] = (cnt[b] > 0) ? atomicAdd(&scount[b], cnt[b]) : 0;
  __syncthreads();
  for (int b = t; b < ncb; b += 256) cnt[b] = 0;
  __syncthreads();
  for (int i = t; i < ne; i += 256) {
    int d = dst[e0 + i], s = src[e0 + i];
    int b = d >> 8;
    int r = atomicAdd(&cnt[b], 1);
    image[lscan[b] + r] =
        (uint32_t)s | ((uint32_t)(d & 255) << 16) | ((uint32_t)b << 24);
  }
  __syncthreads();
  for (int j = t; j < ne; j += 256) {
    uint32_t w = image[j];
    int b = w >> 24;
    int pos = gbase[b] + (j - lscan[b]);
    if (pos < CAPC) tmp[(size_t)b * CAPC + pos] = w & 0xFFFFFFu;
  }
}

// ---------------- bucketB body: key = dst_local*8 + src_block --------------
// Direct scatter to csr_src (contiguous ~32KB window per block). 8.2KB LDS.
__device__ __forceinline__ void bucketB_body(
    int b, char* smem, const uint32_t* __restrict__ tmp,
    const int* __restrict__ scount, int* __restrict__ row_start,
    int* __restrict__ csr_src, int n, int ncb, int e, int sshift) {
  int* cnt2 = (int*)smem;                      // 2048 (hist -> cursor)
  int* wsum = cnt2 + 2048;                     // 4
  int* s_base = wsum + 4;                      // 1
  const int t = threadIdx.x, lane = t & 63, wid = t >> 6;

  if (t < 64) {
    int part = 0;
    for (int idx = lane; idx < b; idx += 64) part += scount[idx];
#pragma unroll
    for (int off = 32; off; off >>= 1) part += __shfl_xor(part, off, 64);
    if (lane == 0) *s_base = part;
  }
#pragma unroll
  for (int j = 0; j < 8; j++) cnt2[t * 8 + j] = 0;
  __syncthreads();
  const int total = min(scount[b], CAPC);
  const int base = *s_base;
  const uint32_t* strm = tmp + (size_t)b * CAPC;

  for (int i = t; i < total; i += 256) {
    uint32_t w = strm[i];
    int key = (((w >> 16) & 255) << 3) + ((w & 0xFFFFu) >> sshift);
    atomicAdd(&cnt2[key], 1);
  }
  __syncthreads();
  int c8[8];
  int run = 0;
#pragma unroll
  for (int j = 0; j < 8; j++) { int x = cnt2[t * 8 + j]; c8[j] = run; run += x; }
  int c = run, v = c;
#pragma unroll
  for (int off = 1; off < 64; off <<= 1) {
    int u = __shfl_up(v, off, 64);
    if (lane >= off) v += u;
  }
  if (lane == 63) wsum[wid] = v;
  __syncthreads();
  if (t == 0) {
    int acc = 0;
#pragma unroll
    for (int w = 0; w < 4; w++) { int x = wsum[w]; wsum[w] = acc; acc += x; }
  }
  __syncthreads();
  int ex = wsum[wid] + v - c;
#pragma unroll
  for (int j = 0; j < 8; j++) cnt2[t * 8 + j] = ex + c8[j];
  int d = b * CBG + t;
  if (d < n) row_start[d] = base + ex;
  if (b == 0 && t == 0) row_start[n] = e;
  __syncthreads();
  // direct scatter into this block's contiguous csr window
  for (int i = t; i < total; i += 256) {
    uint32_t w = strm[i];
    uint32_t s = w & 0xFFFFu;
    int key = (((w >> 16) & 255) << 3) + (s >> sshift);
    int pos = atomicAdd(&cnt2[key], 1);
    csr_src[base + pos] = (int)s;
  }
}

// ---------------- MFMA GEMM body (uses caller LDS; 34.8KB) ----------------
template <int MODE>
__device__ __forceinline__ void mfmm_body(
    int bid, char* smem,
    const uint32_t* __restrict__ Xp, const short* __restrict__ Whi,
    const short* __restrict__ Wlo, const float* __restrict__ bias,
    uint32_t* __restrict__ Hp, uint32_t* __restrict__ zp,
    float2* __restrict__ el2, float2* __restrict__ er2,
    const float* __restrict__ al, const float* __restrict__ ar, int n,
    const float* __restrict__ emb, const int* __restrict__ ids,
    const float* __restrict__ feat) {
  short* Ahi = (short*)smem;
  short* Alo = Ahi + 64 * 136;
  const int t = threadIdx.x;
  const int nb = bid * 64;

  for (int idx = t; idx < 64 * 32; idx += 256) {
    int nl = idx >> 5, k4 = (idx & 31) << 2;
    int node = nb + nl;
    uint32_t h01 = 0, h23 = 0, l01 = 0, l23 = 0;
    if (node < n) {
      if (MODE == 1) {
        uint4 w = *(const uint4*)&Xp[(size_t)node * 128 + k4];
        h01 = (w.x >> 16) | (w.y & 0xffff0000u);
        l01 = (w.x & 0xffffu) | (w.y << 16);
        h23 = (w.z >> 16) | (w.w & 0xffff0000u);
        l23 = (w.z & 0xffffu) | (w.w << 16);
      } else {
        float4 v;
        if (k4 < 64) v = *(const float4*)&emb[(size_t)ids[node] * 64 + k4];
        else         v = *(const float4*)&feat[(size_t)node * 64 + (k4 - 64)];
        uint32_t a0 = bf16_rne(v.x), a1 = bf16_rne(v.y);
        uint32_t a2 = bf16_rne(v.z), a3 = bf16_rne(v.w);
        h01 = a0 | (a1 << 16);
        h23 = a2 | (a3 << 16);
        l01 = bf16_rne(v.x - __uint_as_float(a0 << 16)) |
              (bf16_rne(v.y - __uint_as_float(a1 << 16)) << 16);
        l23 = bf16_rne(v.z - __uint_as_float(a2 << 16)) |
              (bf16_rne(v.w - __uint_as_float(a3 << 16)) << 16);
      }
    }
    *(uint2*)&Ahi[nl * 136 + k4] = make_uint2(h01, h23);
    *(uint2*)&Alo[nl * 136 + k4] = make_uint2(l01, l23);
  }
  __syncthreads();

  const int lane = t & 63, wv = t >> 6;
  const int r16 = lane & 15, g = lane >> 4;
  const int arow = (wv * 16 + r16) * 136;

  f32x4 acc[8];
#pragma unroll
  for (int c = 0; c < 8; c++) acc[c] = (f32x4){0.f, 0.f, 0.f, 0.f};

#pragma unroll
  for (int q = 0; q < 4; q++) {
    int ka = q * 32 + g * 8;
    short8v ahi = *(const short8v*)&Ahi[arow + ka];
    short8v alo = *(const short8v*)&Alo[arow + ka];
#pragma unroll
    for (int c = 0; c < 8; c++) {
      short8v bhi = *(const short8v*)&Whi[(((q * 8 + c) * 64) + lane) * 8];
      short8v blo = *(const short8v*)&Wlo[(((q * 8 + c) * 64) + lane) * 8];
      acc[c] = __builtin_amdgcn_mfma_f32_16x16x32_bf16(ahi, bhi, acc[c], 0, 0, 0);
      acc[c] = __builtin_amdgcn_mfma_f32_16x16x32_bf16(ahi, blo, acc[c], 0, 0, 0);
      acc[c] = __builtin_amdgcn_mfma_f32_16x16x32_bf16(alo, bhi, acc[c], 0, 0, 0);
    }
  }

  const int node_base = nb + wv * 16;
  if (MODE == 0) {
#pragma unroll
    for (int c = 0; c < 8; c++) {
      int col = c * 16 + r16;
      float bv = bias[col];
#pragma unroll
      for (int r = 0; r < 4; r++) {
        int node = node_base + g * 4 + r;
        if (node < n) {
          float v = fmaxf(acc[c][r] + bv, 0.f);
          Hp[(size_t)node * 128 + col] = pack_hilo(v);
        }
      }
    }
  } else {
    float p0l[4] = {0, 0, 0, 0}, p1l[4] = {0, 0, 0, 0};
    float p0r[4] = {0, 0, 0, 0}, p1r[4] = {0, 0, 0, 0};
#pragma unroll
    for (int c = 0; c < 8; c++) {
      int col = c * 16 + r16;
      float av = al[col], rv = ar[col];
#pragma unroll
      for (int r = 0; r < 4; r++) {
        if (c < 4) { p0l[r] = fmaf(acc[c][r], av, p0l[r]); p0r[r] = fmaf(acc[c][r], rv, p0r[r]); }
        else       { p1l[r] = fmaf(acc[c][r], av, p1l[r]); p1r[r] = fmaf(acc[c][r], rv, p1r[r]); }
      }
    }
#pragma unroll
    for (int c = 0; c < 8; c++) {
#pragma unroll
      for (int r = 0; r < 4; r++) {
        float other = __shfl_xor(acc[c][r], 1, 64);
        int node = node_base + g * 4 + r;
        if (!(lane & 1) && node < n) {
          uint32_t w = bf16_rne(acc[c][r]) | (bf16_rne(other) << 16);
          zp[(size_t)node * 64 + c * 8 + (r16 >> 1)] = w;
        }
      }
    }
#pragma unroll
    for (int off = 1; off < 16; off <<= 1) {
#pragma unroll
      for (int r = 0; r < 4; r++) {
        p0l[r] += __shfl_xor(p0l[r], off, 64);
        p1l[r] += __shfl_xor(p1l[r], off, 64);
        p0r[r] += __shfl_xor(p0r[r], off, 64);
        p1r[r] += __shfl_xor(p1r[r], off, 64);
      }
    }
    if (r16 == 0) {
#pragma unroll
      for (int r = 0; r < 4; r++) {
        int node = node_base + g * 4 + r;
        if (node < n) {
          el2[node] = make_float2(p0l[r], p1l[r]);
          er2[node] = make_float2(p0r[r], p1r[r]);
        }
      }
    }
  }
}

// ---- fusedA: bucketA (blocks [0,nA)) || dense GEMM (disjoint buffers) ----
__global__ __launch_bounds__(256) void fusedA_kernel(
    const int* __restrict__ src, const int* __restrict__ dst,
    int* __restrict__ scount, uint32_t* __restrict__ tmp, int e, int ncb, int nA,
    const short* __restrict__ Whi, const short* __restrict__ Wlo,
    const float* __restrict__ bias, uint32_t* __restrict__ Hp, int n,
    const float* __restrict__ emb, const int* __restrict__ ids,
    const float* __restrict__ feat) {
  __shared__ __align__(16) char smem[34816];
  if ((int)blockIdx.x < nA) {
    bucketA_body(blockIdx.x, smem, src, dst, scount, tmp, e, ncb);
  } else {
    mfmm_body<0>(blockIdx.x - nA, smem, nullptr, Whi, Wlo, bias, Hp,
                 nullptr, nullptr, nullptr, nullptr, nullptr, n, emb, ids, feat);
  }
}

// ---- fusedB: bucketB (blocks [0,ncbB)) || layer-1 z-GEMM (disjoint) ------
__global__ __launch_bounds__(256) void fusedB_kernel(
    const uint32_t* __restrict__ tmp, const int* __restrict__ scount,
    int* __restrict__ row_start, int* __restrict__ csr_src, int ncbB,
    int n, int ncb, int e, int sshift,
    const uint32_t* __restrict__ Xp, const short* __restrict__ Whi,
    const short* __restrict__ Wlo, uint32_t* __restrict__ zp,
    float2* __restrict__ el2, float2* __restrict__ er2,
    const float* __restrict__ al, const float* __restrict__ ar) {
  __shared__ __align__(16) char smem[34816];
  if ((int)blockIdx.x < ncbB) {
    bucketB_body(blockIdx.x, smem, tmp, scount, row_start, csr_src, n, ncb, e,
                 sshift);
  } else {
    mfmm_body<1>(blockIdx.x - ncbB, smem, Xp, Whi, Wlo, nullptr, nullptr, zp,
                 el2, er2, al, ar, n, nullptr, nullptr, nullptr);
  }
}

__global__ __launch_bounds__(256) void mfmm1_kernel(
    const uint32_t* __restrict__ Xp, const short* __restrict__ Whi,
    const short* __restrict__ Wlo, uint32_t* __restrict__ zp,
    float2* __restrict__ el2, float2* __restrict__ er2,
    const float* __restrict__ al, const float* __restrict__ ar, int n) {
  __shared__ __align__(16) char smem[34816];
  mfmm_body<1>(blockIdx.x, smem, Xp, Whi, Wlo, nullptr, nullptr, zp, el2, er2,
               al, ar, n, nullptr, nullptr, nullptr);
}

// ---------------- fallback path (n >= 65536) ----------------
__global__ void hist_kernel(const int* __restrict__ dst, int* __restrict__ cnt, int e) {
  for (int i = blockIdx.x * blockDim.x + threadIdx.x; i < e; i += gridDim.x * blockDim.x)
    atomicAdd(&cnt[dst[i]], 1);
}
__global__ void scatter_kernel(const int* __restrict__ src, const int* __restrict__ dst,
                               const int* __restrict__ row_start, int* __restrict__ cursor,
                               int* __restrict__ csr_src, int e) {
  for (int i = blockIdx.x * blockDim.x + threadIdx.x; i < e; i += gridDim.x * blockDim.x) {
    int d = dst[i];
    int pos = atomicAdd(&cursor[d], 1);
    csr_src[row_start[d] + pos] = src[i];
  }
}
__global__ __launch_bounds__(1024) void scan1_kernel(const int* __restrict__ cnt,
                                                     int* __restrict__ row_start,
                                                     int* __restrict__ bsum, int n) {
  __shared__ int wsum[16];
  const int t = threadIdx.x, lane = t & 63, wid = t >> 6;
  int i = blockIdx.x * 1024 + t;
  int c = (i < n) ? cnt[i] : 0;
  int v = c;
#pragma unroll
  for (int off = 1; off < 64; off <<= 1) {
    int u = __shfl_up(v, off, 64);
    if (lane >= off) v += u;
  }
  if (lane == 63) wsum[wid] = v;
  __syncthreads();
  if (t == 0) {
    int acc = 0;
#pragma unroll
    for (int w = 0; w < 16; w++) { int x = wsum[w]; wsum[w] = acc; acc += x; }
    bsum[blockIdx.x] = acc;
  }
  __syncthreads();
  if (i < n) row_start[i] = wsum[wid] + v - c;
}
__global__ __launch_bounds__(64) void scan2_kernel(int* __restrict__ bsum, int nb) {
  const int lane = threadIdx.x;
  int carry = 0;
  for (int base = 0; base < nb; base += 64) {
    int idx = base + lane;
    int c = (idx < nb) ? bsum[idx] : 0;
    int v = c;
#pragma unroll
    for (int off = 1; off < 64; off <<= 1) {
      int u = __shfl_up(v, off, 64);
      if (lane >= off) v += u;
    }
    if (idx < nb) bsum[idx] = carry + v - c;
    carry += __shfl(v, 63, 64);
  }
}
__global__ void scan3_kernel(int* __restrict__ row_start, const int* __restrict__ bsum,
                             int n, int e) {
  int i = blockIdx.x * blockDim.x + threadIdx.x;
  if (i < n) row_start[i] += bsum[i >> 10];
  if (i == 0) row_start[n] = e;
}

// ---------------- GAT aggregation (wave per dst node) -- r14 version -------
#define CAP 256
__global__ __launch_bounds__(256) void agg12_kernel(
    const uint32_t* __restrict__ zp, const float2* __restrict__ el2,
    const float2* __restrict__ er2, const int* __restrict__ row_start,
    const int* __restrict__ csr_src, const float* __restrict__ bias,
    uint32_t* __restrict__ Hp,
    const float* __restrict__ ow, const float* __restrict__ oal,
    const float* __restrict__ oar, float2* __restrict__ zel,
    float* __restrict__ er3, int n, int fuse_out) {
  __shared__ float ecf[4][2][CAP];
  __shared__ int sc[4][CAP];
  const int w = threadIdx.x >> 6, lane = threadIdx.x & 63;
  const int node = blockIdx.x * 4 + w;
  const bool valid = node < n;
  int rs = 0, deg = 0;
  float er0 = 0.f, er1 = 0.f;
  if (valid) {
    rs = row_start[node];
    deg = row_start[node + 1] - rs;
    float2 e2 = er2[node];
    er0 = e2.x; er1 = e2.y;
  }
  const int cdeg = deg < CAP ? deg : CAP;

  float sp0 = 0.f, sp1 = 0.f;
  for (int i = lane; i < deg; i += 64) {
    int s = csr_src[rs + i];
    float2 l = el2[s];
    float x0 = __expf(lrelu(l.x + er0));
    float x1 = __expf(lrelu(l.y + er1));
    if (i < CAP) { sc[w][i] = s << 8; ecf[w][0][i] = x0; ecf[w][1][i] = x1; }
    sp0 += x0; sp1 += x1;
  }
#pragma unroll
  for (int off = 32; off; off >>= 1) {
    sp0 += __shfl_xor(sp0, off, 64);
    sp1 += __shfl_xor(sp1, off, 64);
  }
  // no __syncthreads(): sc/ecf slices are per-wave (write+read by same wave)

  const float* exh = ecf[w][lane >> 5];
  const char* zpB = (const char*)zp + (size_t)lane * 4;
  float ae = 0.f, ao = 0.f;
  int i = 0;
  for (; i + 8 <= cdeg; i += 8) {
    uint32_t zw[8];
    float xh[8];
#pragma unroll
    for (int u = 0; u < 8; u++) {
      int off = sc[w][i + u];
      xh[u] = exh[i + u];
      zw[u] = *(const uint32_t*)(zpB + off);
    }
#pragma unroll
    for (int u = 0; u < 8; u++) {
      ae = fmaf(xh[u], __uint_as_float(zw[u] << 16), ae);
      ao = fmaf(xh[u], __uint_as_float(zw[u] & 0xffff0000u), ao);
    }
  }
  for (; i < cdeg; i++) {
    int off = sc[w][i];
    float x = exh[i];
    uint32_t zw = *(const uint32_t*)(zpB + off);
    ae = fmaf(x, __uint_as_float(zw << 16), ae);
    ao = fmaf(x, __uint_as_float(zw & 0xffff0000u), ao);
  }
  for (; i < deg; i++) {  // beyond-CAP tail (not hit for this graph)
    int s = csr_src[rs + i];
    float2 l = el2[s];
    float x0 = __expf(lrelu(l.x + er0));
    float x1 = __expf(lrelu(l.y + er1));
    float x = (lane < 32) ? x0 : x1;
    uint32_t zw = *(const uint32_t*)(zpB + ((size_t)s << 8));
    ae = fmaf(x, __uint_as_float(zw << 16), ae);
    ao = fmaf(x, __uint_as_float(zw & 0xffff0000u), ao);
  }

  if (valid) {
    float sp = (lane < 32) ? sp0 : sp1;
    float2 b2 = reinterpret_cast<const float2*>(bias)[lane];
    float oe, oo;
    if (deg == 0) { oe = b2.x; oo = b2.y; }
    else { oe = ae / sp + b2.x; oo = ao / sp + b2.y; }
    oe = fmaxf(oe, 0.f);
    oo = fmaxf(oo, 0.f);
    if (!fuse_out) {
      *(uint2*)&Hp[(size_t)node * 128 + 2 * lane] =
          make_uint2(pack_hilo(oe), pack_hilo(oo));
    } else {
      float2 w2 = reinterpret_cast<const float2*>(ow)[lane];
      float d = oe * w2.x + oo * w2.y;
#pragma unroll
      for (int off = 32; off; off >>= 1) d += __shfl_xor(d, off, 64);
      if (lane == 0) {
        zel[node] = make_float2(d, d * oal[0]);  // (z3, el3) packed
        er3[node] = d * oar[0];
      }
    }
  }
}

// ---------------- output GAT layer: 32-lane group per node -----------------
// (z3,el3) packed as float2 -> ONE 8B random gather per edge.
__global__ __launch_bounds__(256) void agg3_kernel(
    const float2* __restrict__ zel, const float* __restrict__ er3,
    const int* __restrict__ row_start, const int* __restrict__ csr_src,
    const float* __restrict__ b, float* __restrict__ out, int n) {
  int node = blockIdx.x * 8 + (threadIdx.x >> 5);
  int l32 = threadIdx.x & 31;
  if (node >= n) return;
  int rs = row_start[node];
  int deg = row_start[node + 1] - rs;
  float er = er3[node];
  float sp = 0.f, ap = 0.f;
  for (int i = l32; i < deg; i += 32) {
    int s = csr_src[rs + i];
    float2 l = zel[s];
    float ex = __expf(lrelu(l.y + er));
    sp += ex;
    ap = fmaf(ex, l.x, ap);
  }
#pragma unroll
  for (int off = 16; off; off >>= 1) {
    sp += __shfl_xor(sp, off, 64);
    ap += __shfl_xor(ap, off, 64);
  }
  if (l32 == 0) out[node] = (deg == 0) ? b[0] : (ap / sp + b[0]);
}

// ---------------------------------------------------------------------------
extern "C" void kernel_launch(void* const* d_in, const int* in_sizes, int n_in,
                              void* d_out, int out_size, void* d_ws, size_t ws_size,
                              hipStream_t stream) {
  const float* feat     = (const float*)d_in[0];
  const int*   node_ids = (const int*)d_in[1];
  const int*   src      = (const int*)d_in[2];
  const int*   dst      = (const int*)d_in[3];
  const float* emb      = (const float*)d_in[4];
  const float* dense_w  = (const float*)d_in[5];
  const float* dense_b  = (const float*)d_in[6];
  const float* g1_w     = (const float*)d_in[7];
  const float* g1_al    = (const float*)d_in[8];
  const float* g1_ar    = (const float*)d_in[9];
  const float* g1_b     = (const float*)d_in[10];
  const float* g2_w     = (const float*)d_in[11];
  const float* g2_al    = (const float*)d_in[12];
  const float* g2_ar    = (const float*)d_in[13];
  const float* g2_b     = (const float*)d_in[14];
  const float* out_w    = (const float*)d_in[15];
  const float* out_al   = (const float*)d_in[16];
  const float* out_ar   = (const float*)d_in[17];
  const float* out_b    = (const float*)d_in[18];
  const int n = in_sizes[0] / 64;   // 50000
  const int e = in_sizes[2];        // 1600000

  const int ncb = (n + CBG - 1) / CBG;
  int lg = 0;
  while ((1 << lg) < n) lg++;
  const int sshift = lg > 3 ? lg - 3 : 0;

  char* ws = (char*)d_ws;
  size_t off = 0;
  auto alloc = [&](size_t bytes) -> void* {
    void* p = ws + off;
    off += (bytes + 255) & ~(size_t)255;
    return p;
  };
  uint32_t* Hp       = (uint32_t*)alloc((size_t)n * 128 * 4);
  uint32_t* zp       = (uint32_t*)alloc((size_t)n * 64 * 4);
  uint32_t* tmp      = (uint32_t*)alloc((size_t)ncb * CAPC * 4);  // no alias
  float2*   el2      = (float2*)alloc((size_t)n * 8);
  float2*   er2      = (float2*)alloc((size_t)n * 8);
  float2*   zel      = (float2*)alloc((size_t)n * 8);
  float*    er3      = (float*)alloc((size_t)n * 4);
  int*      scount   = (int*)alloc((size_t)ncb * 4);
  int*      row_start= (int*)alloc((size_t)(n + 1) * 4);
  int*      csr_src  = (int*)alloc((size_t)e * 4);
  short*    Wd_hi    = (short*)alloc(2048 * 8 * 2);
  short*    Wd_lo    = (short*)alloc(2048 * 8 * 2);
  short*    W1_hi    = (short*)alloc(2048 * 8 * 2);
  short*    W1_lo    = (short*)alloc(2048 * 8 * 2);
  short*    W2_hi    = (short*)alloc(2048 * 8 * 2);
  short*    W2_lo    = (short*)alloc(2048 * 8 * 2);
  // fallback-only buffers
  int*      cnt      = (int*)alloc((size_t)n * 4);
  int*      cursor   = (int*)alloc((size_t)n * 4);
  const int nblk     = (n + 1023) / 1024;
  int*      bsum     = (int*)alloc((size_t)nblk * 4);

  const int mmgrid = (n + 63) / 64;
  const int ngrid4 = (n + 3) / 4;
  const int ngrid8 = (n + 7) / 8;

  // prep: W split+swizzle + scount zero
  prep_kernel<<<25, 256, 0, stream>>>(dense_w, g1_w, g2_w,
                                      Wd_hi, Wd_lo, W1_hi, W1_lo, W2_hi, W2_lo,
                                      scount, ncb);

  if (n < 65536) {
    const int natile = (e + TILE - 1) / TILE;
    // fusedA: bucketA || dense GEMM
    fusedA_kernel<<<natile + mmgrid, 256, 0, stream>>>(
        src, dst, scount, tmp, e, ncb, natile,
        Wd_hi, Wd_lo, dense_b, Hp, n, emb, node_ids, feat);
    // fusedB: bucketB || layer-1 z-GEMM (both 34.8KB LDS -> 4 blocks/CU)
    fusedB_kernel<<<ncb + mmgrid, 256, 0, stream>>>(
        tmp, scount, row_start, csr_src, ncb, n, ncb, e, sshift,
        Hp, W1_hi, W1_lo, zp, el2, er2, g1_al, g1_ar);
  } else {
    hipMemsetAsync(cnt, 0, (size_t)n * 4, stream);
    hipMemsetAsync(cursor, 0, (size_t)n * 4, stream);
    hist_kernel<<<2048, 256, 0, stream>>>(dst, cnt, e);
    scan1_kernel<<<nblk, 1024, 0, stream>>>(cnt, row_start, bsum, n);
    scan2_kernel<<<1, 64, 0, stream>>>(bsum, nblk);
    scan3_kernel<<<(n + 255) / 256, 256, 0, stream>>>(row_start, bsum, n, e);
    scatter_kernel<<<2048, 256, 0, stream>>>(src, dst, row_start, cursor, csr_src, e);
    fusedA_kernel<<<mmgrid, 256, 0, stream>>>(
        src, dst, scount, tmp, e, ncb, 0,
        Wd_hi, Wd_lo, dense_b, Hp, n, emb, node_ids, feat);
    fusedB_kernel<<<mmgrid, 256, 0, stream>>>(
        tmp, scount, row_start, csr_src, 0, n, ncb, e, sshift,
        Hp, W1_hi, W1_lo, zp, el2, er2, g1_al, g1_ar);
  }

  // GAT layer 1 aggregation
  agg12_kernel<<<ngrid4, 256, 0, stream>>>(zp, el2, er2, row_start, csr_src, g1_b, Hp,
                                           nullptr, nullptr, nullptr, nullptr, nullptr,
                                           n, 0);
  // GAT layer 2 z-GEMM + aggregation (fused output-layer zel/er3)
  mfmm1_kernel<<<mmgrid, 256, 0, stream>>>(Hp, W2_hi, W2_lo, zp, el2, er2,
                                           g2_al, g2_ar, n);
  agg12_kernel<<<ngrid4, 256, 0, stream>>>(zp, el2, er2, row_start, csr_src, g2_b, nullptr,
                                           out_w, out_al, out_ar, zel, er3, n, 1);
  // output GAT layer aggregation
  agg3_kernel<<<ngrid8, 256, 0, stream>>>(zel, er3, row_start, csr_src, out_b,
                                          (float*)d_out, n);
}